// Round 9
// baseline (201.774 us; speedup 1.0000x reference)
//
#include <hip/hip_runtime.h>

#define S_LEN 2048
#define NHQ 8
#define NKV 2
#define HD 256
#define KVB 32

typedef __attribute__((ext_vector_type(8))) short bf16x8;
typedef __attribute__((ext_vector_type(4))) short bf16x4;
typedef __attribute__((ext_vector_type(4))) float f32x4;
typedef __attribute__((ext_vector_type(16))) float f32x16;
typedef __attribute__((ext_vector_type(4))) unsigned u32x4;

__device__ __forceinline__ short f2bf(float f) {
    unsigned u = __builtin_bit_cast(unsigned, f);
    u += 0x7FFFu + ((u >> 16) & 1u);
    return (short)(u >> 16);
}
__device__ __forceinline__ float bf2f(short s) {
    unsigned u = ((unsigned)(unsigned short)s) << 16;
    return __builtin_bit_cast(float, u);
}
__device__ __forceinline__ unsigned cvtpk(float a, float b) {
    unsigned r;
    asm("v_cvt_pk_bf16_f32 %0, %1, %2" : "=v"(r) : "v"(a), "v"(b));
    return r;
}
__device__ __forceinline__ void gload16(const short* g, short* l) {
    __builtin_amdgcn_global_load_lds((const __attribute__((address_space(1))) unsigned*)g,
                                     (__attribute__((address_space(3))) unsigned*)l, 16, 0, 0);
}
__device__ __forceinline__ float bperm(int srclane, float v) {
    return __builtin_bit_cast(float,
        __builtin_amdgcn_ds_bpermute(srclane * 4, __builtin_bit_cast(int, v)));
}

// ---------------- fp32 -> bf16 convert ----------------
__global__ __launch_bounds__(256) void cvt_kernel(const float* __restrict__ in,
                                                  short* __restrict__ out, int n) {
    int i = (blockIdx.x * 256 + threadIdx.x) * 4;
    if (i + 3 < n) {
        float4 f = *(const float4*)(in + i);
        bf16x4 o;
        o[0] = f2bf(f.x); o[1] = f2bf(f.y); o[2] = f2bf(f.z); o[3] = f2bf(f.w);
        *(bf16x4*)(out + i) = o;
    }
}

// ---------------- fp32 W[K][N] -> bf16 Wt[N][K] (convert + transpose) -------
__global__ __launch_bounds__(256) void wt_kernel(const float* __restrict__ in,
                                                 short* __restrict__ out,
                                                 int K, int N) {
    __shared__ short tile[64][72];
    int n0 = blockIdx.x * 64, k0 = blockIdx.y * 64;
    int t = threadIdx.x;
    #pragma unroll
    for (int i = 0; i < 16; i++) {
        int flat = i * 256 + t; int r = flat >> 6, c = flat & 63;
        tile[r][c] = f2bf(in[(long)(k0 + r) * N + n0 + c]);
    }
    __syncthreads();
    #pragma unroll
    for (int i = 0; i < 16; i++) {
        int flat = i * 256 + t; int r = flat >> 6, c = flat & 63;
        out[(long)(n0 + r) * K + k0 + c] = tile[c][r];
    }
}

// ---------------- m97-style GEMM: C[M][N] = A[M][K] @ Bt[N][K]^T ------------
template<int BN, int WRITE_BF16>
__global__ __launch_bounds__(256) void gemm_bt(const short* __restrict__ A,
                                               const short* __restrict__ Bt,
                                               void* __restrict__ Cv,
                                               int M, int N, int K) {
    constexpr int NI = BN / 32;          // B-frags per wave
    __shared__ short As[128 * 32];
    __shared__ short Bs[BN * 32];
    const int t = threadIdx.x;
    const int lane = t & 63, w = t >> 6;
    const int lr = lane & 15, lg = lane >> 4;
    const int m0 = blockIdx.y * 128, n0 = blockIdx.x * BN;
    const int wm = (w >> 1) * 64, wn = (w & 1) * (BN / 2);

    f32x4 acc[4][NI];
    #pragma unroll
    for (int i = 0; i < 4; i++)
        #pragma unroll
        for (int j = 0; j < NI; j++) acc[i][j] = (f32x4){0.f, 0.f, 0.f, 0.f};

    for (int k0 = 0; k0 < K; k0 += 32) {
        __syncthreads();
        #pragma unroll
        for (int r = 0; r < 2; r++) {            // A tile: 128x32 = 8 KB
            int sbase = r * 2048 + w * 512;
            int srow = (sbase + lane * 8) >> 5, scol = (sbase + lane * 8) & 31;
            gload16(A + (long)(m0 + srow) * K + k0 + scol, &As[sbase]);
        }
        #pragma unroll
        for (int r = 0; r < BN / 64; r++) {      // B tile: BNx32
            int sbase = r * 2048 + w * 512;
            int srow = (sbase + lane * 8) >> 5, scol = (sbase + lane * 8) & 31;
            gload16(Bt + (long)(n0 + srow) * K + k0 + scol, &Bs[sbase]);
        }
        __syncthreads();
        bf16x8 af[4], bfr[NI];
        #pragma unroll
        for (int mi = 0; mi < 4; mi++)
            af[mi] = *(const bf16x8*)&As[(wm + mi * 16 + lr) * 32 + lg * 8];
        #pragma unroll
        for (int ni = 0; ni < NI; ni++)
            bfr[ni] = *(const bf16x8*)&Bs[(wn + ni * 16 + lr) * 32 + lg * 8];
        #pragma unroll
        for (int mi = 0; mi < 4; mi++)
            #pragma unroll
            for (int ni = 0; ni < NI; ni++)
                acc[mi][ni] = __builtin_amdgcn_mfma_f32_16x16x32_bf16(af[mi], bfr[ni], acc[mi][ni], 0, 0, 0);
    }
    #pragma unroll
    for (int mi = 0; mi < 4; mi++)
    #pragma unroll
    for (int ni = 0; ni < NI; ni++)
    #pragma unroll
    for (int r = 0; r < 4; r++) {
        long row = m0 + wm + mi * 16 + lg * 4 + r;
        long col = n0 + wn + ni * 16 + lr;
        float v = acc[mi][ni][r];
        if (WRITE_BF16) ((short*)Cv)[row * N + col] = f2bf(v);
        else            ((float*)Cv)[row * N + col] = v;
    }
}

// ---------------- RMSNorm + partial RoPE (K path) ---------------------------
__global__ __launch_bounds__(256) void norm_rope_kernel(
    const short* __restrict__ in, short* __restrict__ out,
    const float* __restrict__ w, const float* __restrict__ cosb,
    const float* __restrict__ sinb, int H, long ldin, long cofs,
    long ob, long oh, long os, float scale) {
    int vec = blockIdx.x * 4 + (threadIdx.x >> 6);
    int lane = threadIdx.x & 63;
    int token = vec / H, head = vec % H;
    int b = token / S_LEN, s = token % S_LEN;

    bf16x4 xv = *(const bf16x4*)(in + (long)token * ldin + cofs + head * 256 + lane * 4);
    float x0 = bf2f(xv[0]), x1 = bf2f(xv[1]), x2 = bf2f(xv[2]), x3 = bf2f(xv[3]);
    float ss = x0 * x0 + x1 * x1 + x2 * x2 + x3 * x3;
    #pragma unroll
    for (int m = 1; m < 64; m <<= 1) ss += __shfl_xor(ss, m);
    float inv = rsqrtf(ss * (1.f / 256.f) + 1e-6f);

    float4 wv = *(const float4*)(w + lane * 4);
    float y0 = x0 * inv * (1.f + wv.x);
    float y1 = x1 * inv * (1.f + wv.y);
    float y2 = x2 * inv * (1.f + wv.z);
    float y3 = x3 * inv * (1.f + wv.w);

    if (lane < 16) {
        float2 c = *(const float2*)&cosb[s * 32 + lane * 2];
        float2 sn = *(const float2*)&sinb[s * 32 + lane * 2];
        float a0 = y0 * c.x - y1 * sn.x, b0 = y0 * sn.x + y1 * c.x;
        float a1 = y2 * c.y - y3 * sn.y, b1 = y2 * sn.y + y3 * c.y;
        y0 = a0; y1 = b0; y2 = a1; y3 = b1;
    }
    y0 *= scale; y1 *= scale; y2 *= scale; y3 *= scale;
    long oidx = (long)b * ob + (long)head * oh + (long)s * os + lane * 4;
    bf16x4 o; o[0] = f2bf(y0); o[1] = f2bf(y1); o[2] = f2bf(y2); o[3] = f2bf(y3);
    *(bf16x4*)(out + oidx) = o;
}

// ---------------- V transpose: C[token][2560+kv*256+d] -> vr[b][kv][d][s] ---
__global__ __launch_bounds__(256) void transpose_v_kernel(const short* __restrict__ C,
                                                          short* __restrict__ vr) {
    __shared__ short tile[64][65];
    int s0 = blockIdx.x * 64, d0 = blockIdx.y * 64;
    int bkv = blockIdx.z; int b = bkv >> 1, kv = bkv & 1;
    int t = threadIdx.x;
    #pragma unroll
    for (int i = 0; i < 16; i++) {
        int flat = i * 256 + t; int si = flat >> 6, di = flat & 63;
        tile[si][di] = C[(long)(b * S_LEN + s0 + si) * 3072 + 2560 + kv * 256 + d0 + di];
    }
    __syncthreads();
    #pragma unroll
    for (int i = 0; i < 16; i++) {
        int flat = i * 256 + t; int di = flat >> 6, si = flat & 63;
        vr[(long)(bkv * 256 + d0 + di) * S_LEN + s0 + si] = tile[si][di];
    }
}

// ---------------- flash attention: split-stage pipeline, balanced halves ----
// 4 waves (2 q-groups x 2 key parities), 64 q rows/block, fused Q norm+rope.
// Per phase: vm8|BAR|QK|BAR|stageK+1|softmax|vm8|BAR|PV|BAR|stageV+1.
__global__ __launch_bounds__(256, 2) void flash_kernel(const short* __restrict__ Cq,
                                                       const short* __restrict__ Kt,
                                                       const short* __restrict__ Vt,
                                                       short* __restrict__ O,
                                                       const float* __restrict__ qnw,
                                                       const float* __restrict__ cosb,
                                                       const float* __restrict__ sinb) {
    // [0,32K): K tiles (parity p at p*16KB); [32K,64K): V tiles; epilogue reuses
    __shared__ __align__(16) char smem[66048];

    int idx = blockIdx.x;
    int half = idx >> 8, rm = idx & 255;
    int xcd = rm & 7, slot = rm >> 3;        // consecutive blocks -> XCD round-robin
    int bh = xcd * 2 + (slot & 1);           // 2 bh per XCD -> 4MB KV in its L2
    int jj = slot >> 1;                      // 0..15
    int j  = half ? jj : (31 - jj);          // CU pair (idx, idx+256): j sums to 31
    int h = bh & 7, b = bh >> 3;
    int kv = h >> 2;
    int t = threadIdx.x, lane = t & 63, w = t >> 6;
    int g = w >> 1, p = w & 1;               // q-group, key parity
    int ln = lane & 31, hi = lane >> 5;
    int q0 = j * 64 + g * 32;
    int qg = q0 + ln;                        // this lane's q row (score column)

    const short* Kb = Kt + (long)(b * NKV + kv) * S_LEN * HD;
    const short* Vb = Vt + (long)(b * NKV + kv) * HD * S_LEN;

    // stage K pair {2*ph2, 2*ph2+1} (8 loads/thread)
    auto stageK = [&](int ph2) {
        #pragma unroll
        for (int pp = 0; pp < 2; pp++) {
            int k0s = (2 * ph2 + pp) * KVB;
            short* Ktile = (short*)(smem + pp * 16384);
            #pragma unroll
            for (int c = 0; c < 4; c++) {
                int o = c * 4096 + w * 1024 + lane * 16;
                int key = o >> 9, db = o & 511;
                gload16(Kb + (long)(k0s + key) * HD + ((db ^ ((key & 7) << 4)) >> 1),
                        Ktile + (c * 4096 + w * 1024) / 2);
            }
        }
    };
    // stage V pair (8 loads/thread)
    auto stageV = [&](int ph2) {
        #pragma unroll
        for (int pp = 0; pp < 2; pp++) {
            int k0s = (2 * ph2 + pp) * KVB;
            short* Vtile = (short*)(smem + 32768 + pp * 16384);
            #pragma unroll
            for (int c = 0; c < 4; c++) {
                int o = c * 4096 + w * 1024 + lane * 16;
                int d = o >> 6, kb = o & 63;
                gload16(Vb + (long)d * S_LEN + k0s + ((kb ^ ((d & 6) << 3)) >> 1),
                        Vtile + (c * 4096 + w * 1024) / 2);
            }
        }
    };

    stageK(0); stageV(0);

    // ---- Q load from fused C + RMSNorm + partial RoPE + 1/16 scale ----
    bf16x8 qf[16];
    {
        const short* qrow = Cq + (long)(b * S_LEN + qg) * 3072 + h * 256 + hi * 8;
        #pragma unroll
        for (int dc = 0; dc < 16; dc++) qf[dc] = *(const bf16x8*)&qrow[dc * 16];
        float ss = 0.f;
        #pragma unroll
        for (int dc = 0; dc < 16; dc++)
            #pragma unroll
            for (int e = 0; e < 8; e++) { float v = bf2f(qf[dc][e]); ss += v * v; }
        ss += __shfl_xor(ss, 32);
        float inv = rsqrtf(ss * (1.f / 256.f) + 1e-6f);
        #pragma unroll
        for (int dc = 0; dc < 16; dc++) {
            float y[8];
            float4 w0 = *(const float4*)&qnw[dc * 16 + hi * 8];
            float4 w1 = *(const float4*)&qnw[dc * 16 + hi * 8 + 4];
            y[0] = bf2f(qf[dc][0]) * inv * (1.f + w0.x);
            y[1] = bf2f(qf[dc][1]) * inv * (1.f + w0.y);
            y[2] = bf2f(qf[dc][2]) * inv * (1.f + w0.z);
            y[3] = bf2f(qf[dc][3]) * inv * (1.f + w0.w);
            y[4] = bf2f(qf[dc][4]) * inv * (1.f + w1.x);
            y[5] = bf2f(qf[dc][5]) * inv * (1.f + w1.y);
            y[6] = bf2f(qf[dc][6]) * inv * (1.f + w1.z);
            y[7] = bf2f(qf[dc][7]) * inv * (1.f + w1.w);
            if (dc < 4) {   // d < 64: rope pairs (2i,2i+1), angle idx d/2
                float4 c4 = *(const float4*)&cosb[qg * 32 + dc * 8 + hi * 4];
                float4 s4 = *(const float4*)&sinb[qg * 32 + dc * 8 + hi * 4];
                float a, bb;
                a = y[0]; bb = y[1]; y[0] = a * c4.x - bb * s4.x; y[1] = a * s4.x + bb * c4.x;
                a = y[2]; bb = y[3]; y[2] = a * c4.y - bb * s4.y; y[3] = a * s4.y + bb * c4.y;
                a = y[4]; bb = y[5]; y[4] = a * c4.z - bb * s4.z; y[5] = a * s4.z + bb * c4.z;
                a = y[6]; bb = y[7]; y[6] = a * c4.w - bb * s4.w; y[7] = a * s4.w + bb * c4.w;
            }
            bf16x8 o;
            #pragma unroll
            for (int e = 0; e < 8; e++) o[e] = f2bf(y[e] * 0.0625f);
            qf[dc] = o;
        }
    }

    f32x16 acc[8];
    #pragma unroll
    for (int i = 0; i < 8; i++)
        #pragma unroll
        for (int r = 0; r < 16; r++) acc[i][r] = 0.f;
    float m = -1e30f, l = 0.f;

    for (int ph = 0; ph <= j; ph++) {
        const bool last = (ph == j);
        asm volatile("s_waitcnt vmcnt(8)" ::: "memory");   // K(ph) landed (all waves)
        __builtin_amdgcn_s_barrier();
        int k0 = (2 * ph + p) * KVB;
        bool act = (k0 <= q0 + 31);

        // ---- QK^T (swapped): s = K * Q, D[key][q]; 2 chains ----
        f32x16 s;
        if (act) {
            const char* Ks = (const char*)smem + p * 16384;
            f32x16 sA, sB;
            #pragma unroll
            for (int r = 0; r < 16; r++) { sA[r] = 0.f; sB[r] = 0.f; }
            __builtin_amdgcn_s_setprio(1);
            #pragma unroll
            for (int dc = 0; dc < 16; dc += 2) {
                int kb0 = (dc * 32 + hi * 16) ^ ((ln & 7) << 4);
                int kb1 = ((dc + 1) * 32 + hi * 16) ^ ((ln & 7) << 4);
                bf16x8 kf0 = *(const bf16x8*)(Ks + ln * 512 + kb0);
                bf16x8 kf1 = *(const bf16x8*)(Ks + ln * 512 + kb1);
                sA = __builtin_amdgcn_mfma_f32_32x32x16_bf16(kf0, qf[dc],     sA, 0, 0, 0);
                sB = __builtin_amdgcn_mfma_f32_32x32x16_bf16(kf1, qf[dc + 1], sB, 0, 0, 0);
            }
            __builtin_amdgcn_s_setprio(0);
            #pragma unroll
            for (int r = 0; r < 16; r++) s[r] = sA[r] + sB[r];
        }
        __builtin_amdgcn_s_barrier();            // all waves done reading K
        if (!last) stageK(ph + 1);               // hidden under softmax + PV
        __builtin_amdgcn_sched_barrier(0);

        // ---- mask + online softmax + P->bf16, fully in-register ----
        bf16x8 pa0, pa1;
        if (act) {
            if (k0 + KVB - 1 > q0) {
                #pragma unroll
                for (int r = 0; r < 16; r++) {
                    int key_g = k0 + (r & 3) + 8 * (r >> 2) + 4 * hi;
                    if (key_g > qg) s[r] = -1e30f;
                }
            }
            float mt = s[0];
            #pragma unroll
            for (int r = 1; r < 16; r++) mt = fmaxf(mt, s[r]);
            mt = fmaxf(mt, __shfl_xor(mt, 32));
            float mn = m;
            if (!__all(mt <= m + 8.f)) {           // defer-max (T13)
                mn = fmaxf(m, mt);
                float f = __expf(m - mn);
                m = mn;
                float fr[16];
                #pragma unroll
                for (int r = 0; r < 16; r++)
                    fr[r] = bperm((r & 3) + 8 * (r >> 2) + 4 * hi, f);
                #pragma unroll
                for (int i = 0; i < 8; i++)
                    #pragma unroll
                    for (int r = 0; r < 16; r++) acc[i][r] *= fr[r];
                l *= f;
            }
            float pr[16], ps = 0.f;
            #pragma unroll
            for (int r = 0; r < 16; r++) { pr[r] = __expf(s[r] - mn); ps += pr[r]; }
            ps += __shfl_xor(ps, 32);
            l += ps;

            unsigned pw[8];
            #pragma unroll
            for (int kc = 0; kc < 2; kc++) {
                unsigned X = cvtpk(pr[kc * 8 + 0], pr[kc * 8 + 1]);
                unsigned Y = cvtpk(pr[kc * 8 + 4], pr[kc * 8 + 5]);
                unsigned Z = cvtpk(pr[kc * 8 + 2], pr[kc * 8 + 3]);
                unsigned W = cvtpk(pr[kc * 8 + 6], pr[kc * 8 + 7]);
                asm volatile("v_permlane32_swap_b32 %0, %1" : "+v"(X), "+v"(Y));
                asm volatile("v_permlane32_swap_b32 %0, %1" : "+v"(Z), "+v"(W));
                pw[kc * 4 + 0] = X; pw[kc * 4 + 1] = Z;
                pw[kc * 4 + 2] = Y; pw[kc * 4 + 3] = W;
            }
            u32x4 w0v = {pw[0], pw[1], pw[2], pw[3]};
            u32x4 w1v = {pw[4], pw[5], pw[6], pw[7]};
            pa0 = __builtin_bit_cast(bf16x8, w0v);
            pa1 = __builtin_bit_cast(bf16x8, w1v);
        }

        if (last) { asm volatile("s_waitcnt vmcnt(0)" ::: "memory"); }
        else      { asm volatile("s_waitcnt vmcnt(8)" ::: "memory"); }  // V(ph) landed
        __builtin_amdgcn_s_barrier();            // V writes visible to all waves

        // ---- PV: acc[db] += P * V ----
        if (act) {
            const char* Vs = (const char*)smem + 32768 + p * 16384;
            __builtin_amdgcn_s_setprio(1);
            #pragma unroll
            for (int db = 0; db < 8; db++) {
                int drow = db * 32 + ln;
                int sw = (drow & 6) << 3;
                bf16x8 vf0 = *(const bf16x8*)(Vs + drow * 64 + ((hi * 16) ^ sw));
                bf16x8 vf1 = *(const bf16x8*)(Vs + drow * 64 + ((32 + hi * 16) ^ sw));
                acc[db] = __builtin_amdgcn_mfma_f32_32x32x16_bf16(pa0, vf0, acc[db], 0, 0, 0);
                acc[db] = __builtin_amdgcn_mfma_f32_32x32x16_bf16(pa1, vf1, acc[db], 0, 0, 0);
            }
            __builtin_amdgcn_s_setprio(0);
        }
        __builtin_amdgcn_s_barrier();            // all waves done reading V
        if (!last) stageV(ph + 1);               // hidden under next QK
    }

    // ---- parity merge epilogue (staging LDS is dead) ----
    float* accb = (float*)smem;                 // [g][128][64] f32
    float* mlb  = (float*)(smem + 65536);       // m: [0,64), l: [64,128)
    if (p == 1) {
        #pragma unroll
        for (int db = 0; db < 8; db++)
            #pragma unroll
            for (int r = 0; r < 16; r++)
                accb[g * 8192 + (db * 16 + r) * 64 + hi * 32 + ln] = acc[db][r];
        if (hi == 0) { mlb[g * 32 + ln] = m; mlb[64 + g * 32 + ln] = l; }
    }
    __syncthreads();
    if (p == 0) {
        float m1 = mlb[g * 32 + ln], l1 = mlb[64 + g * 32 + ln];
        float M  = fmaxf(m, m1);
        float f0 = __expf(m - M), f1 = __expf(m1 - M);
        float lt = l * f0 + l1 * f1;
        float w0 = f0 / lt, w1 = f1 / lt;
        float fr0[16], fr1[16];
        #pragma unroll
        for (int r = 0; r < 16; r++) {
            int crow = (r & 3) + 8 * (r >> 2) + 4 * hi;
            fr0[r] = bperm(crow, w0);
            fr1[r] = bperm(crow, w1);
        }
        #pragma unroll
        for (int db = 0; db < 8; db++)
            #pragma unroll
            for (int r = 0; r < 16; r++) {
                float a1 = accb[g * 8192 + (db * 16 + r) * 64 + hi * 32 + ln];
                int qrow = q0 + (r & 3) + 8 * (r >> 2) + 4 * hi;
                O[(long)(b * S_LEN + qrow) * 2048 + h * HD + db * 32 + ln] =
                    f2bf(acc[db][r] * fr0[r] + a1 * fr1[r]);
            }
    }
}

extern "C" void kernel_launch(void* const* d_in, const int* in_sizes, int n_in,
                              void* d_out, int out_size, void* d_ws, size_t ws_size,
                              hipStream_t stream) {
    const float* x    = (const float*)d_in[0];
    const float* cosb = (const float*)d_in[1];
    const float* sinb = (const float*)d_in[2];
    // d_in[3] = mask: equivalent to causal; computed analytically in-kernel
    const float* wq   = (const float*)d_in[4];
    const float* wk   = (const float*)d_in[5];
    const float* wv   = (const float*)d_in[6];
    const float* wo   = (const float*)d_in[7];
    const float* qnw  = (const float*)d_in[8];
    const float* knw  = (const float*)d_in[9];
    float* out = (float*)d_out;

    char* ws = (char*)d_ws;
    short* xb   = (short*)(ws + 0);          // 4096x512 bf16               [0, 4194304)
    short* wfus = (short*)(ws + 4194304);    // [3072][512] wq|wk|wv^T      [4194304, 7340032)
    short* wot  = (short*)(ws + 7340032);    // [512][2048] wo^T            [7340032, 9437184)
    short* C    = (short*)(ws + 9437184);    // 4096x3072 fused QKV out     [9437184, 34603008)
    short* ao   = (short*)(ws + 34603008);   // flash out (C stays live: Q source)
    short* kr   = (short*)(ws + 51380224);   // [b][kv][s][d] 4 MB          [51380224, 55574528)
    short* vr   = (short*)(ws + 55574528);   // [b][kv][d][s] 4 MB          [55574528, 59768832)

    cvt_kernel<<<2048, 256, 0, stream>>>(x, xb, 2097152);
    wt_kernel<<<dim3(32, 8), 256, 0, stream>>>(wq, wfus,              512, 2048);
    wt_kernel<<<dim3(8, 8),  256, 0, stream>>>(wk, wfus + 2048 * 512, 512, 512);
    wt_kernel<<<dim3(8, 8),  256, 0, stream>>>(wv, wfus + 2560 * 512, 512, 512);
    wt_kernel<<<dim3(8, 32), 256, 0, stream>>>(wo, wot, 2048, 512);

    // fused QKV projection: C[4096][3072]
    gemm_bt<128, 1><<<dim3(24, 32), 256, 0, stream>>>(xb, wfus, C, 4096, 3072, 512);

    // K norm+rope -> kr ; V transpose -> vr (Q norm+rope fused into flash)
    norm_rope_kernel<<<2048, 256, 0, stream>>>(C, kr, knw, cosb, sinb, 2,
                                               3072L, 2048L, 1048576L, 524288L, 256L, 1.0f);
    transpose_v_kernel<<<dim3(32, 4, 4), 256, 0, stream>>>(C, vr);

    flash_kernel<<<512, 256, 0, stream>>>(C, kr, vr, ao, qnw, cosb, sinb);

    gemm_bt<64, 0><<<dim3(8, 32), 256, 0, stream>>>(ao, wot, out, 4096, 512, 2048);
}